// Round 1
// baseline (870.272 us; speedup 1.0000x reference)
//
#include <hip/hip_runtime.h>
#include <math.h>

#define BB 8
#define TT 2048
#define EE 1024
#define HH 64
#define RROWS 16   // rows per block in projection
#define QT 32      // query rows per attention block
#define KT 64      // key tile

// ---------------- QKV projection ----------------
// grid: (B*T/RROWS) blocks, 256 threads.
// Stage RROWS x-rows in LDS; threads 0..191 each own one (matrix, h) column.
__global__ __launch_bounds__(256) void qkv_proj(
    const float* __restrict__ x,
    const float* __restrict__ Wk, const float* __restrict__ bk,
    const float* __restrict__ Wq, const float* __restrict__ bq,
    const float* __restrict__ Wv, const float* __restrict__ bv,
    float* __restrict__ qo, float* __restrict__ ko, float* __restrict__ vo) {
  __shared__ float xs[RROWS * EE];
  const int tid = threadIdx.x;
  const long row0 = (long)blockIdx.x * RROWS;

  // stage x rows (float4, coalesced)
  const float4* xg = (const float4*)(x + row0 * EE);
  float4* xs4 = (float4*)xs;
  #pragma unroll
  for (int i = 0; i < RROWS * EE / 4 / 256; ++i)
    xs4[i * 256 + tid] = xg[i * 256 + tid];
  __syncthreads();

  const int tg = tid >> 6;  // wave id: 0->K, 1->Q, 2->V, 3 idle
  if (tg < 3) {
    const int h = tid & 63;
    const float* W    = (tg == 0) ? Wk : (tg == 1) ? Wq : Wv;
    const float* bias = (tg == 0) ? bk : (tg == 1) ? bq : bv;
    float* out        = (tg == 0) ? ko : (tg == 1) ? qo : vo;

    float acc[RROWS];
    #pragma unroll
    for (int r = 0; r < RROWS; ++r) acc[r] = 0.f;

    for (int e = 0; e < EE; e += 4) {
      const float w0 = W[(e + 0) * HH + h];
      const float w1 = W[(e + 1) * HH + h];
      const float w2 = W[(e + 2) * HH + h];
      const float w3 = W[(e + 3) * HH + h];
      #pragma unroll
      for (int r = 0; r < RROWS; ++r) {
        const float4 xv = *(const float4*)&xs[r * EE + e];
        acc[r] = fmaf(xv.x, w0, acc[r]);
        acc[r] = fmaf(xv.y, w1, acc[r]);
        acc[r] = fmaf(xv.z, w2, acc[r]);
        acc[r] = fmaf(xv.w, w3, acc[r]);
      }
    }
    const float bb = bias[h];
    #pragma unroll
    for (int r = 0; r < RROWS; ++r)
      out[(row0 + r) * HH + h] = acc[r] + bb;
  }
}

// ---------------- causal flash attention ----------------
// grid: (T/QT, B), 256 threads. Thread owns (row r = tid>>3, colgroup cg = tid&7).
__global__ __launch_bounds__(256) void attn_fwd(
    const float* __restrict__ qv, const float* __restrict__ kv,
    const float* __restrict__ vv, float* __restrict__ out) {
  __shared__ float Qs[QT][HH + 1];
  __shared__ float Ks[KT][HH + 1];
  __shared__ float Vs[KT][HH + 1];
  __shared__ float Ps[QT][KT + 1];

  const int tid = threadIdx.x;
  const int b = blockIdx.y;
  const int qt = blockIdx.x;
  const int q0 = qt * QT;
  const long base = (long)b * TT;
  const int r = tid >> 3, cg = tid & 7;

  // load Q tile
  #pragma unroll
  for (int i = 0; i < QT * HH / 256; ++i) {
    const int flat = i * 256 + tid;
    Qs[flat >> 6][flat & 63] = qv[(base + q0 + (flat >> 6)) * HH + (flat & 63)];
  }

  float m = -INFINITY, l = 0.f;
  float acc[8];
  #pragma unroll
  for (int i = 0; i < 8; ++i) acc[i] = 0.f;

  const int ntiles = (q0 + QT - 1) / KT + 1;
  for (int t = 0; t < ntiles; ++t) {
    const int s0 = t * KT;
    __syncthreads();  // previous iter done reading Ks/Vs/Ps (also covers Q load)
    #pragma unroll
    for (int i = 0; i < KT * HH / 256; ++i) {
      const int flat = i * 256 + tid;
      const int rr = flat >> 6, cc = flat & 63;
      Ks[rr][cc] = kv[(base + s0 + rr) * HH + cc];
      Vs[rr][cc] = vv[(base + s0 + rr) * HH + cc];
    }
    __syncthreads();

    // scores: S[r][cg*8+j] = q[r] . k[cg*8+j]
    float sj[8];
    #pragma unroll
    for (int j = 0; j < 8; ++j) sj[j] = 0.f;
    for (int e = 0; e < HH; ++e) {
      const float qe = Qs[r][e];
      #pragma unroll
      for (int j = 0; j < 8; ++j)
        sj[j] = fmaf(qe, Ks[cg * 8 + j][e], sj[j]);
    }

    const int qi = q0 + r;
    float rmax = -INFINITY;
    #pragma unroll
    for (int j = 0; j < 8; ++j) {
      sj[j] = (s0 + cg * 8 + j <= qi) ? sj[j] * 0.125f : -INFINITY;
      rmax = fmaxf(rmax, sj[j]);
    }
    rmax = fmaxf(rmax, __shfl_xor(rmax, 1));
    rmax = fmaxf(rmax, __shfl_xor(rmax, 2));
    rmax = fmaxf(rmax, __shfl_xor(rmax, 4));

    const float mn = fmaxf(m, rmax);
    const float rescale = __expf(m - mn);
    float psum = 0.f;
    #pragma unroll
    for (int j = 0; j < 8; ++j) { sj[j] = __expf(sj[j] - mn); psum += sj[j]; }
    psum += __shfl_xor(psum, 1);
    psum += __shfl_xor(psum, 2);
    psum += __shfl_xor(psum, 4);
    l = l * rescale + psum;
    m = mn;
    #pragma unroll
    for (int i = 0; i < 8; ++i) acc[i] *= rescale;

    #pragma unroll
    for (int j = 0; j < 8; ++j) Ps[r][cg * 8 + j] = sj[j];
    __syncthreads();

    // PV: acc[i] += sum_j P[r][j] * V[j][cg*8+i]
    #pragma unroll
    for (int j = 0; j < KT; ++j) {
      const float pj = Ps[r][j];
      #pragma unroll
      for (int i = 0; i < 8; ++i)
        acc[i] = fmaf(pj, Vs[j][cg * 8 + i], acc[i]);
    }
  }

  const float inv_l = 1.f / l;
  #pragma unroll
  for (int i = 0; i < 8; ++i)
    out[(base + q0 + r) * HH + cg * 8 + i] = acc[i] * inv_l;
}

extern "C" void kernel_launch(void* const* d_in, const int* in_sizes, int n_in,
                              void* d_out, int out_size, void* d_ws, size_t ws_size,
                              hipStream_t stream) {
  const float* x  = (const float*)d_in[0];
  const float* Wk = (const float*)d_in[1];
  const float* bk = (const float*)d_in[2];
  const float* Wq = (const float*)d_in[3];
  const float* bq = (const float*)d_in[4];
  const float* Wv = (const float*)d_in[5];
  const float* bv = (const float*)d_in[6];
  float* out = (float*)d_out;

  float* qb = (float*)d_ws;
  float* kb = qb + (size_t)BB * TT * HH;
  float* vb = kb + (size_t)BB * TT * HH;

  qkv_proj<<<dim3(BB * TT / RROWS), 256, 0, stream>>>(x, Wk, bk, Wq, bq, Wv, bv,
                                                      qb, kb, vb);
  attn_fwd<<<dim3(TT / QT, BB), 256, 0, stream>>>(qb, kb, vb, out);
}

// Round 2
// 112.140 us; speedup vs baseline: 7.7606x; 7.7606x over previous
//
#include <hip/hip_runtime.h>
#include <math.h>

#define BB 8
#define TT 2048
#define EE 1024
#define HH 64
// 1/sqrt(64) * log2(e): fold into q so scores are in exp2 domain
#define QSCALE 0.18033688011112042f

typedef __attribute__((ext_vector_type(8))) short short8;
typedef __attribute__((ext_vector_type(4))) float f32x4;
typedef __attribute__((ext_vector_type(4))) unsigned short us4;

__device__ inline unsigned short f2bf(float f) {
  union { float f; unsigned u; } v; v.f = f;
  unsigned r = v.u + 0x7FFFu + ((v.u >> 16) & 1u);  // RNE
  return (unsigned short)(r >> 16);
}

// ---------- prep: Wt[m][h][e] = W_m[e][h] (bf16), m: 0=k 1=q(scaled) 2=v ----
__global__ __launch_bounds__(256) void prep_w(
    const float* __restrict__ Wk, const float* __restrict__ Wq,
    const float* __restrict__ Wv, unsigned short* __restrict__ Wt) {
  const int o = blockIdx.x * 256 + threadIdx.x;  // 3*64*1024 = 196608
  const int e = o & 1023;
  const int h = (o >> 10) & 63;
  const int m = o >> 16;
  const float* W = (m == 0) ? Wk : (m == 1) ? Wq : Wv;
  float v = W[e * 64 + h];
  if (m == 1) v *= QSCALE;
  Wt[o] = f2bf(v);
}

// ---------- QKV projection: MFMA GEMM, 64 M-rows/block, N=192 --------------
// outputs: kb/qb row-major [B*T][64] bf16 (q pre-scaled), vt [B][64][T] bf16
__global__ __launch_bounds__(256) void qkv_proj(
    const float* __restrict__ x,
    const float* __restrict__ bk, const float* __restrict__ bq,
    const float* __restrict__ bv, const unsigned short* __restrict__ Wt,
    unsigned short* __restrict__ kb, unsigned short* __restrict__ qb,
    unsigned short* __restrict__ vt) {
  __shared__ alignas(16) unsigned short xs[64][40];  // 32 e-cols padded to 40

  const int tid = threadIdx.x;
  const long row0 = (long)blockIdx.x * 64;
  const int w = tid >> 6, lane = tid & 63;
  const int q = lane & 15, g = lane >> 4;

  const f32x4 z = {0.f, 0.f, 0.f, 0.f};
  f32x4 acc[12];
  #pragma unroll
  for (int i = 0; i < 12; ++i) acc[i] = z;

  for (int e0 = 0; e0 < EE; e0 += 32) {
    __syncthreads();  // previous iter done reading xs
    #pragma unroll
    for (int it = 0; it < 2; ++it) {
      const int flat = it * 256 + tid;
      const int r = flat >> 3, f4 = flat & 7;
      const float4 xv = *(const float4*)&x[(row0 + r) * EE + e0 + f4 * 4];
      us4 pk = {f2bf(xv.x), f2bf(xv.y), f2bf(xv.z), f2bf(xv.w)};
      *(us4*)&xs[r][f4 * 4] = pk;
    }
    __syncthreads();

    const short8 af = *(const short8*)&xs[16 * w + q][g * 8];
    #pragma unroll
    for (int m = 0; m < 3; ++m) {
      #pragma unroll
      for (int hb = 0; hb < 4; ++hb) {
        const short8 bf =
            *(const short8*)&Wt[((m * 64 + hb * 16 + q) << 10) + e0 + g * 8];
        acc[m * 4 + hb] =
            __builtin_amdgcn_mfma_f32_16x16x32_bf16(af, bf, acc[m * 4 + hb], 0, 0, 0);
      }
    }
  }

  // epilogue: D[row=4g+r][col=h-local=q]
  #pragma unroll
  for (int m = 0; m < 3; ++m) {
    #pragma unroll
    for (int hb = 0; hb < 4; ++hb) {
      const int h = hb * 16 + q;
      float bias = (m == 0) ? bk[h] : (m == 1) ? bq[h] * QSCALE : bv[h];
      const f32x4 a = acc[m * 4 + hb];
      #pragma unroll
      for (int r = 0; r < 4; ++r) {
        const long row = row0 + 16 * w + 4 * g + r;
        const unsigned short ov = f2bf(a[r] + bias);
        if (m == 0) kb[row * 64 + h] = ov;
        else if (m == 1) qb[row * 64 + h] = ov;
        else {
          const long bi = row >> 11, tl = row & 2047;
          vt[(bi * 64 + h) * TT + tl] = ov;
        }
      }
    }
  }
}

// ---------- flash attention, swapped-operand MFMA ---------------------------
// S^T = mfma(K, Q): lane holds S^T[key=4g+r][qcol=lane&15] -> per-lane softmax.
// O^T = mfma(V^T, P^T). Waves: w&1 = key-half, w>>1 = strip pair slot.
__global__ __launch_bounds__(256) void attn_fwd(
    const unsigned short* __restrict__ qb, const unsigned short* __restrict__ kb,
    const unsigned short* __restrict__ vt, float* __restrict__ out) {
  __shared__ alignas(16) unsigned short PsT[4][16][40];  // per wave [q][key]
  __shared__ float accT[2][64][17];
  __shared__ float mlb[2][2][16];

  const int tid = threadIdx.x;
  const int w = tid >> 6, lane = tid & 63;
  const int q = lane & 15, g = lane >> 4;

  const int b = blockIdx.x & 7;
  const int pidx = blockIdx.x >> 3;  // 0..63
  const int pr = w >> 1;             // pair slot (0/1) within block
  const int hf = w & 1;              // key half
  const int s = (pr == 0) ? pidx : (127 - pidx);
  const int q0 = s * 16;
  const long base = (long)b * TT;

  const int ntiles = (s + 2) >> 1;   // ceil((s+1)*16 / 32)
  const int n0 = ntiles >> 1;
  const int t_lo = hf ? n0 : 0;
  const int t_hi = hf ? ntiles : n0;

  // Q fragments (held whole kernel): B[k=h][col=q], k contiguous per lane
  const short8 Qf0 = *(const short8*)&qb[(base + q0 + q) * 64 + g * 8];
  const short8 Qf1 = *(const short8*)&qb[(base + q0 + q) * 64 + 32 + g * 8];

  const f32x4 z = {0.f, 0.f, 0.f, 0.f};
  float m = -INFINITY, l = 0.f;
  f32x4 o0 = z, o1 = z, o2 = z, o3 = z;
  const int qg = q0 + q;

  for (int t = t_lo; t < t_hi; ++t) {
    const int k0 = t * 32;
    // K A-frags: A[row=key-local=lane&15][k=h contiguous]
    const unsigned short* kp = &kb[(base + k0 + q) * 64];
    const short8 K00 = *(const short8*)&kp[g * 8];
    const short8 K01 = *(const short8*)&kp[32 + g * 8];
    const short8 K10 = *(const short8*)&kp[16 * 64 + g * 8];
    const short8 K11 = *(const short8*)&kp[16 * 64 + 32 + g * 8];

    f32x4 sa = __builtin_amdgcn_mfma_f32_16x16x32_bf16(K00, Qf0, z, 0, 0, 0);
    sa = __builtin_amdgcn_mfma_f32_16x16x32_bf16(K01, Qf1, sa, 0, 0, 0);
    f32x4 sb = __builtin_amdgcn_mfma_f32_16x16x32_bf16(K10, Qf0, z, 0, 0, 0);
    sb = __builtin_amdgcn_mfma_f32_16x16x32_bf16(K11, Qf1, sb, 0, 0, 0);

    // causal mask: key = k0 + kblk*16 + 4g + r  vs  q-row qg
    if (k0 + 31 > q0) {
      #pragma unroll
      for (int r = 0; r < 4; ++r) {
        if (k0 + 4 * g + r > qg) sa[r] = -INFINITY;
        if (k0 + 16 + 4 * g + r > qg) sb[r] = -INFINITY;
      }
    }

    // online softmax (exp2 domain; per-lane rows, reduce only across g)
    float tmax = fmaxf(fmaxf(fmaxf(sa[0], sa[1]), fmaxf(sa[2], sa[3])),
                       fmaxf(fmaxf(sb[0], sb[1]), fmaxf(sb[2], sb[3])));
    tmax = fmaxf(tmax, __shfl_xor(tmax, 16));
    tmax = fmaxf(tmax, __shfl_xor(tmax, 32));
    const float nm = fmaxf(m, tmax);
    const float rs = __builtin_amdgcn_exp2f(m - nm);  // m=-inf -> 0
    float p[8], ps = 0.f;
    #pragma unroll
    for (int r = 0; r < 4; ++r) { p[r] = __builtin_amdgcn_exp2f(sa[r] - nm); ps += p[r]; }
    #pragma unroll
    for (int r = 0; r < 4; ++r) { p[4 + r] = __builtin_amdgcn_exp2f(sb[r] - nm); ps += p[4 + r]; }
    ps += __shfl_xor(ps, 16);
    ps += __shfl_xor(ps, 32);
    l = l * rs + ps;
    m = nm;
    o0 *= rs; o1 *= rs; o2 *= rs; o3 *= rs;

    // V^T A-frags: A[row=h-local=lane&15][k=key contiguous]
    const unsigned short* vp = &vt[((long)b * 64 + q) * TT + k0];
    const short8 V0 = *(const short8*)&vp[g * 8];
    const short8 V1 = *(const short8*)&vp[16 * TT + g * 8];
    const short8 V2 = *(const short8*)&vp[32 * TT + g * 8];
    const short8 V3 = *(const short8*)&vp[48 * TT + g * 8];

    // P^T via per-wave LDS: write [q][key=4g..], read B-frag [q][8g..8g+7]
    us4 plo = {f2bf(p[0]), f2bf(p[1]), f2bf(p[2]), f2bf(p[3])};
    us4 phi = {f2bf(p[4]), f2bf(p[5]), f2bf(p[6]), f2bf(p[7])};
    *(us4*)&PsT[w][q][4 * g] = plo;
    *(us4*)&PsT[w][q][16 + 4 * g] = phi;
    const short8 Pf = *(const short8*)&PsT[w][q][8 * g];

    o0 = __builtin_amdgcn_mfma_f32_16x16x32_bf16(V0, Pf, o0, 0, 0, 0);
    o1 = __builtin_amdgcn_mfma_f32_16x16x32_bf16(V1, Pf, o1, 0, 0, 0);
    o2 = __builtin_amdgcn_mfma_f32_16x16x32_bf16(V2, Pf, o2, 0, 0, 0);
    o3 = __builtin_amdgcn_mfma_f32_16x16x32_bf16(V3, Pf, o3, 0, 0, 0);
  }

  // merge the two key-halves of each strip
  if (hf == 1) {
    #pragma unroll
    for (int hb = 0; hb < 4; ++hb) {
      const f32x4 a = (hb == 0) ? o0 : (hb == 1) ? o1 : (hb == 2) ? o2 : o3;
      #pragma unroll
      for (int r = 0; r < 4; ++r) accT[pr][16 * hb + 4 * g + r][q] = a[r];
    }
    mlb[pr][0][q] = m;  // replicated across g: same value
    mlb[pr][1][q] = l;
  }
  __syncthreads();
  if (hf == 0) {
    const float m1 = mlb[pr][0][q], l1 = mlb[pr][1][q];
    const float M = fmaxf(m, m1);
    const float f0 = __builtin_amdgcn_exp2f(m - M);
    const float f1 = __builtin_amdgcn_exp2f(m1 - M);
    const float invL = 1.f / (l * f0 + l1 * f1);
    #pragma unroll
    for (int hb = 0; hb < 4; ++hb) {
      const f32x4 a = (hb == 0) ? o0 : (hb == 1) ? o1 : (hb == 2) ? o2 : o3;
      #pragma unroll
      for (int r = 0; r < 4; ++r) {
        const float v =
            (a[r] * f0 + accT[pr][16 * hb + 4 * g + r][q] * f1) * invL;
        out[(base + q0 + q) * 64 + 16 * hb + 4 * g + r] = v;
      }
    }
  }
}

extern "C" void kernel_launch(void* const* d_in, const int* in_sizes, int n_in,
                              void* d_out, int out_size, void* d_ws, size_t ws_size,
                              hipStream_t stream) {
  const float* x  = (const float*)d_in[0];
  const float* Wk = (const float*)d_in[1];
  const float* bk = (const float*)d_in[2];
  const float* Wq = (const float*)d_in[3];
  const float* bq = (const float*)d_in[4];
  const float* Wv = (const float*)d_in[5];
  const float* bv = (const float*)d_in[6];
  float* out = (float*)d_out;

  unsigned short* qbuf = (unsigned short*)d_ws;            // [B*T][64]
  unsigned short* kbuf = qbuf + (size_t)BB * TT * HH;      // [B*T][64]
  unsigned short* vtb  = kbuf + (size_t)BB * TT * HH;      // [B][64][T]
  unsigned short* Wt   = vtb + (size_t)BB * TT * HH;       // [3][64][1024]

  prep_w<<<dim3(768), 256, 0, stream>>>(Wk, Wq, Wv, Wt);
  qkv_proj<<<dim3(256), 256, 0, stream>>>(x, bk, bq, bv, Wt, kbuf, qbuf, vtb);
  attn_fwd<<<dim3(512), 256, 0, stream>>>(qbuf, kbuf, vtb, out);
}

// Round 3
// 69.707 us; speedup vs baseline: 12.4847x; 1.6087x over previous
//
#include <hip/hip_runtime.h>
#include <hip/hip_bf16.h>
#include <math.h>

#define BB 8
#define TT 2048
#define EE 1024
#define HH 64
// 1/sqrt(64) * log2(e): fold into q so scores are in exp2 domain
#define QSCALE 0.18033688011112042f

typedef __attribute__((ext_vector_type(8))) short short8;
typedef __attribute__((ext_vector_type(4))) float f32x4;
typedef __attribute__((ext_vector_type(4))) unsigned short us4;

__device__ inline unsigned short f2bf(float f) {
  union { __hip_bfloat16 h; unsigned short u; } cv;
  cv.h = __float2bfloat16(f);
  return cv.u;
}

// ---------- prep: fragment-ordered weights --------------------------------
// Wf[t][ks][lane][j] = W_m[e][h] * (m==1 ? QSCALE : 1)
//   t = m*4 + hb (12 tiles of 16 N-cols), ks = K-step (32 of them)
//   h = (t&3)*16 + (lane&15), e = ks*32 + (lane>>4)*8 + j
__global__ __launch_bounds__(256) void prep_w(
    const float* __restrict__ Wk, const float* __restrict__ Wq,
    const float* __restrict__ Wv, unsigned short* __restrict__ Wf) {
  const int idx = blockIdx.x * 256 + threadIdx.x;  // 12*32*64 = 24576
  const int lane = idx & 63, ks = (idx >> 6) & 31, t = idx >> 11;
  const int q = lane & 15, g = lane >> 4;
  const int m = t >> 2, h = (t & 3) * 16 + q;
  const float* W = (m == 0) ? Wk : (m == 1) ? Wq : Wv;
  const float sc = (m == 1) ? QSCALE : 1.f;
  const int e0 = ks * 32 + g * 8;
  unsigned short v[8];
  #pragma unroll
  for (int j = 0; j < 8; ++j) v[j] = f2bf(W[(e0 + j) * 64 + h] * sc);
  *(short8*)&Wf[(size_t)idx * 8] = *(short8*)v;
}

// ---------- QKV projection: barrier-free MFMA GEMM ------------------------
// 16 M-rows/block, 1024 blocks, 4 waves. Wave w owns N-tiles {w, 4+w, 8+w}
// (one per matrix m=0,1,2 at hb=w). A staged once in LDS; B coalesced from Wf.
__global__ __launch_bounds__(256) void qkv_proj(
    const float* __restrict__ x,
    const float* __restrict__ bk, const float* __restrict__ bq,
    const float* __restrict__ bv, const unsigned short* __restrict__ Wf,
    unsigned short* __restrict__ kb, unsigned short* __restrict__ qb,
    unsigned short* __restrict__ vt) {
  __shared__ alignas(16) unsigned short xs[16][1032];  // pad 8 -> 2-way max

  const int tid = threadIdx.x;
  const long row0 = (long)blockIdx.x * 16;
  const int w = tid >> 6, lane = tid & 63;
  const int q = lane & 15, g = lane >> 4;

  // stage x-tile: 16 rows x 1024 cols fp32 -> bf16, coalesced
  const float4* xg = (const float4*)&x[row0 * EE];
  #pragma unroll
  for (int i = 0; i < 16; ++i) {
    const int flat = i * 256 + tid;           // 0..4095
    const int rr = flat >> 8, c4 = flat & 255;
    const float4 xv = xg[flat];
    us4 pk = {f2bf(xv.x), f2bf(xv.y), f2bf(xv.z), f2bf(xv.w)};
    *(us4*)&xs[rr][c4 * 4] = pk;
  }
  __syncthreads();

  const f32x4 z = {0.f, 0.f, 0.f, 0.f};
  f32x4 acc0 = z, acc1 = z, acc2 = z;
  const unsigned short* wf0 = &Wf[(size_t)w * 16384 + (size_t)lane * 8];

  #pragma unroll 8
  for (int ks = 0; ks < 32; ++ks) {
    const short8 af = *(const short8*)&xs[q][ks * 32 + g * 8];
    const short8 b0 = *(const short8*)&wf0[ks * 512];
    const short8 b1 = *(const short8*)&wf0[65536 + ks * 512];
    const short8 b2 = *(const short8*)&wf0[131072 + ks * 512];
    acc0 = __builtin_amdgcn_mfma_f32_16x16x32_bf16(af, b0, acc0, 0, 0, 0);
    acc1 = __builtin_amdgcn_mfma_f32_16x16x32_bf16(af, b1, acc1, 0, 0, 0);
    acc2 = __builtin_amdgcn_mfma_f32_16x16x32_bf16(af, b2, acc2, 0, 0, 0);
  }

  // epilogue: D[row=4g+r][col=q], h = w*16+q
  const int h = w * 16 + q;
  const float biask = bk[h], biasq = bq[h] * QSCALE, biasv = bv[h];
  #pragma unroll
  for (int r = 0; r < 4; ++r) {
    const long row = row0 + 4 * g + r;
    kb[row * 64 + h] = f2bf(acc0[r] + biask);
    qb[row * 64 + h] = f2bf(acc1[r] + biasq);
    const long bi = row >> 11, tl = row & 2047;
    vt[(bi * 64 + h) * TT + tl] = f2bf(acc2[r] + biasv);
  }
}

// ---------- flash attention, swapped-operand MFMA ---------------------------
// S^T = mfma(K, Q): lane holds S^T[key=4g+r][qcol=lane&15] -> per-lane softmax.
// O^T = mfma(V^T, P^T). Waves: w&1 = key-half, w>>1 = strip pair slot.
__global__ __launch_bounds__(256) void attn_fwd(
    const unsigned short* __restrict__ qb, const unsigned short* __restrict__ kb,
    const unsigned short* __restrict__ vt, float* __restrict__ out) {
  __shared__ alignas(16) unsigned short PsT[4][16][40];  // per wave [q][key]
  __shared__ float accT[2][64][17];
  __shared__ float mlb[2][2][16];

  const int tid = threadIdx.x;
  const int w = tid >> 6, lane = tid & 63;
  const int q = lane & 15, g = lane >> 4;

  const int b = blockIdx.x & 7;
  const int pidx = blockIdx.x >> 3;  // 0..63
  const int pr = w >> 1;             // pair slot (0/1) within block
  const int hf = w & 1;              // key half
  const int s = (pr == 0) ? pidx : (127 - pidx);
  const int q0 = s * 16;
  const long base = (long)b * TT;

  const int ntiles = (s + 2) >> 1;   // ceil((s+1)*16 / 32)
  const int n0 = ntiles >> 1;
  const int t_lo = hf ? n0 : 0;
  const int t_hi = hf ? ntiles : n0;

  // Q fragments (held whole kernel): B[k=h][col=q], k contiguous per lane
  const short8 Qf0 = *(const short8*)&qb[(base + q0 + q) * 64 + g * 8];
  const short8 Qf1 = *(const short8*)&qb[(base + q0 + q) * 64 + 32 + g * 8];

  const f32x4 z = {0.f, 0.f, 0.f, 0.f};
  float m = -INFINITY, l = 0.f;
  f32x4 o0 = z, o1 = z, o2 = z, o3 = z;
  const int qg = q0 + q;

  for (int t = t_lo; t < t_hi; ++t) {
    const int k0 = t * 32;
    // K A-frags: A[row=key-local=lane&15][k=h contiguous]
    const unsigned short* kp = &kb[(base + k0 + q) * 64];
    const short8 K00 = *(const short8*)&kp[g * 8];
    const short8 K01 = *(const short8*)&kp[32 + g * 8];
    const short8 K10 = *(const short8*)&kp[16 * 64 + g * 8];
    const short8 K11 = *(const short8*)&kp[16 * 64 + 32 + g * 8];

    f32x4 sa = __builtin_amdgcn_mfma_f32_16x16x32_bf16(K00, Qf0, z, 0, 0, 0);
    sa = __builtin_amdgcn_mfma_f32_16x16x32_bf16(K01, Qf1, sa, 0, 0, 0);
    f32x4 sb = __builtin_amdgcn_mfma_f32_16x16x32_bf16(K10, Qf0, z, 0, 0, 0);
    sb = __builtin_amdgcn_mfma_f32_16x16x32_bf16(K11, Qf1, sb, 0, 0, 0);

    // causal mask: key = k0 + kblk*16 + 4g + r  vs  q-row qg
    if (k0 + 31 > q0) {
      #pragma unroll
      for (int r = 0; r < 4; ++r) {
        if (k0 + 4 * g + r > qg) sa[r] = -INFINITY;
        if (k0 + 16 + 4 * g + r > qg) sb[r] = -INFINITY;
      }
    }

    // online softmax (exp2 domain; per-lane rows, reduce only across g)
    float tmax = fmaxf(fmaxf(fmaxf(sa[0], sa[1]), fmaxf(sa[2], sa[3])),
                       fmaxf(fmaxf(sb[0], sb[1]), fmaxf(sb[2], sb[3])));
    tmax = fmaxf(tmax, __shfl_xor(tmax, 16));
    tmax = fmaxf(tmax, __shfl_xor(tmax, 32));
    const float nm = fmaxf(m, tmax);
    const float rs = __builtin_amdgcn_exp2f(m - nm);  // m=-inf -> 0
    float p[8], ps = 0.f;
    #pragma unroll
    for (int r = 0; r < 4; ++r) { p[r] = __builtin_amdgcn_exp2f(sa[r] - nm); ps += p[r]; }
    #pragma unroll
    for (int r = 0; r < 4; ++r) { p[4 + r] = __builtin_amdgcn_exp2f(sb[r] - nm); ps += p[4 + r]; }
    ps += __shfl_xor(ps, 16);
    ps += __shfl_xor(ps, 32);
    l = l * rs + ps;
    m = nm;
    o0 *= rs; o1 *= rs; o2 *= rs; o3 *= rs;

    // V^T A-frags: A[row=h-local=lane&15][k=key contiguous]
    const unsigned short* vp = &vt[((long)b * 64 + q) * TT + k0];
    const short8 V0 = *(const short8*)&vp[g * 8];
    const short8 V1 = *(const short8*)&vp[16 * TT + g * 8];
    const short8 V2 = *(const short8*)&vp[32 * TT + g * 8];
    const short8 V3 = *(const short8*)&vp[48 * TT + g * 8];

    // P^T via per-wave LDS: write [q][key=4g..], read B-frag [q][8g..8g+7]
    us4 plo = {f2bf(p[0]), f2bf(p[1]), f2bf(p[2]), f2bf(p[3])};
    us4 phi = {f2bf(p[4]), f2bf(p[5]), f2bf(p[6]), f2bf(p[7])};
    *(us4*)&PsT[w][q][4 * g] = plo;
    *(us4*)&PsT[w][q][16 + 4 * g] = phi;
    const short8 Pf = *(const short8*)&PsT[w][q][8 * g];

    o0 = __builtin_amdgcn_mfma_f32_16x16x32_bf16(V0, Pf, o0, 0, 0, 0);
    o1 = __builtin_amdgcn_mfma_f32_16x16x32_bf16(V1, Pf, o1, 0, 0, 0);
    o2 = __builtin_amdgcn_mfma_f32_16x16x32_bf16(V2, Pf, o2, 0, 0, 0);
    o3 = __builtin_amdgcn_mfma_f32_16x16x32_bf16(V3, Pf, o3, 0, 0, 0);
  }

  // merge the two key-halves of each strip
  if (hf == 1) {
    #pragma unroll
    for (int hb = 0; hb < 4; ++hb) {
      const f32x4 a = (hb == 0) ? o0 : (hb == 1) ? o1 : (hb == 2) ? o2 : o3;
      #pragma unroll
      for (int r = 0; r < 4; ++r) accT[pr][16 * hb + 4 * g + r][q] = a[r];
    }
    mlb[pr][0][q] = m;  // replicated across g: same value
    mlb[pr][1][q] = l;
  }
  __syncthreads();
  if (hf == 0) {
    const float m1 = mlb[pr][0][q], l1 = mlb[pr][1][q];
    const float M = fmaxf(m, m1);
    const float f0 = __builtin_amdgcn_exp2f(m - M);
    const float f1 = __builtin_amdgcn_exp2f(m1 - M);
    const float invL = 1.f / (l * f0 + l1 * f1);
    #pragma unroll
    for (int hb = 0; hb < 4; ++hb) {
      const f32x4 a = (hb == 0) ? o0 : (hb == 1) ? o1 : (hb == 2) ? o2 : o3;
      #pragma unroll
      for (int r = 0; r < 4; ++r) {
        const float v =
            (a[r] * f0 + accT[pr][16 * hb + 4 * g + r][q] * f1) * invL;
        out[(base + q0 + q) * 64 + 16 * hb + 4 * g + r] = v;
      }
    }
  }
}

extern "C" void kernel_launch(void* const* d_in, const int* in_sizes, int n_in,
                              void* d_out, int out_size, void* d_ws, size_t ws_size,
                              hipStream_t stream) {
  const float* x  = (const float*)d_in[0];
  const float* Wk = (const float*)d_in[1];
  const float* bk = (const float*)d_in[2];
  const float* Wq = (const float*)d_in[3];
  const float* bq = (const float*)d_in[4];
  const float* Wv = (const float*)d_in[5];
  const float* bv = (const float*)d_in[6];
  float* out = (float*)d_out;

  unsigned short* qbuf = (unsigned short*)d_ws;            // [B*T][64]
  unsigned short* kbuf = qbuf + (size_t)BB * TT * HH;      // [B*T][64]
  unsigned short* vtb  = kbuf + (size_t)BB * TT * HH;      // [B][64][T]
  unsigned short* Wf   = vtb + (size_t)BB * TT * HH;       // [12][32][64][8]

  prep_w<<<dim3(96), 256, 0, stream>>>(Wk, Wq, Wv, Wf);
  qkv_proj<<<dim3(1024), 256, 0, stream>>>(x, bk, bq, bv, Wf, kbuf, qbuf, vtb);
  attn_fwd<<<dim3(512), 256, 0, stream>>>(qbuf, kbuf, vtb, out);
}

// Round 4
// 67.132 us; speedup vs baseline: 12.9636x; 1.0384x over previous
//
#include <hip/hip_runtime.h>
#include <hip/hip_bf16.h>
#include <math.h>

#define BB 8
#define TT 2048
#define EE 1024
#define HH 64
// 1/sqrt(64) * log2(e): fold into q so scores are in exp2 domain
#define QSCALE 0.18033688011112042f

typedef __attribute__((ext_vector_type(8))) short short8;
typedef __attribute__((ext_vector_type(4))) float f32x4;
typedef __attribute__((ext_vector_type(4))) unsigned short us4;

__device__ inline unsigned short f2bf(float f) {
  union { __hip_bfloat16 h; unsigned short u; } cv;
  cv.h = __float2bfloat16(f);
  return cv.u;
}

// ---------- prep: fragment-ordered weights --------------------------------
// Wf[t][ks][lane][j] = W_m[e][h] * (m==1 ? QSCALE : 1)
//   t = m*4 + hb (12 tiles of 16 N-cols), ks = K-step (32 of them)
//   h = (t&3)*16 + (lane&15), e = ks*32 + (lane>>4)*8 + j
__global__ __launch_bounds__(256) void prep_w(
    const float* __restrict__ Wk, const float* __restrict__ Wq,
    const float* __restrict__ Wv, unsigned short* __restrict__ Wf) {
  const int idx = blockIdx.x * 256 + threadIdx.x;  // 12*32*64 = 24576
  const int lane = idx & 63, ks = (idx >> 6) & 31, t = idx >> 11;
  const int q = lane & 15, g = lane >> 4;
  const int m = t >> 2, h = (t & 3) * 16 + q;
  const float* W = (m == 0) ? Wk : (m == 1) ? Wq : Wv;
  const float sc = (m == 1) ? QSCALE : 1.f;
  const int e0 = ks * 32 + g * 8;
  unsigned short v[8];
  #pragma unroll
  for (int j = 0; j < 8; ++j) v[j] = f2bf(W[(e0 + j) * 64 + h] * sc);
  *(short8*)&Wf[(size_t)idx * 8] = *(short8*)v;
}

// ---------- QKV projection: barrier-free MFMA GEMM ------------------------
// 16 M-rows/block, 1024 blocks, 4 waves. Wave w owns N-tiles {w, 4+w, 8+w}.
// A staged once in LDS; B coalesced from Wf; explicit depth-1 prefetch.
__global__ __launch_bounds__(256) void qkv_proj(
    const float* __restrict__ x,
    const float* __restrict__ bk, const float* __restrict__ bq,
    const float* __restrict__ bv, const unsigned short* __restrict__ Wf,
    unsigned short* __restrict__ kb, unsigned short* __restrict__ qb,
    unsigned short* __restrict__ vt) {
  __shared__ alignas(16) unsigned short xs[16][1032];  // pad 8 -> 2-way max

  const int tid = threadIdx.x;
  const long row0 = (long)blockIdx.x * 16;
  const int w = tid >> 6, lane = tid & 63;
  const int q = lane & 15, g = lane >> 4;

  // stage x-tile: 16 rows x 1024 cols fp32 -> bf16, coalesced
  const float4* xg = (const float4*)&x[row0 * EE];
  #pragma unroll
  for (int i = 0; i < 16; ++i) {
    const int flat = i * 256 + tid;           // 0..4095
    const int rr = flat >> 8, c4 = flat & 255;
    const float4 xv = xg[flat];
    us4 pk = {f2bf(xv.x), f2bf(xv.y), f2bf(xv.z), f2bf(xv.w)};
    *(us4*)&xs[rr][c4 * 4] = pk;
  }
  __syncthreads();

  const f32x4 z = {0.f, 0.f, 0.f, 0.f};
  f32x4 acc0 = z, acc1 = z, acc2 = z;
  const unsigned short* wf0 = &Wf[(size_t)w * 16384 + (size_t)lane * 8];

  short8 a  = *(const short8*)&xs[q][g * 8];
  short8 b0 = *(const short8*)&wf0[0];
  short8 b1 = *(const short8*)&wf0[65536];
  short8 b2 = *(const short8*)&wf0[131072];

  #pragma unroll
  for (int ks = 0; ks < 31; ++ks) {
    // prefetch next K-step while MFMAs run on current
    const short8 an  = *(const short8*)&xs[q][(ks + 1) * 32 + g * 8];
    const short8 b0n = *(const short8*)&wf0[(ks + 1) * 512];
    const short8 b1n = *(const short8*)&wf0[65536 + (ks + 1) * 512];
    const short8 b2n = *(const short8*)&wf0[131072 + (ks + 1) * 512];
    acc0 = __builtin_amdgcn_mfma_f32_16x16x32_bf16(a, b0, acc0, 0, 0, 0);
    acc1 = __builtin_amdgcn_mfma_f32_16x16x32_bf16(a, b1, acc1, 0, 0, 0);
    acc2 = __builtin_amdgcn_mfma_f32_16x16x32_bf16(a, b2, acc2, 0, 0, 0);
    a = an; b0 = b0n; b1 = b1n; b2 = b2n;
  }
  acc0 = __builtin_amdgcn_mfma_f32_16x16x32_bf16(a, b0, acc0, 0, 0, 0);
  acc1 = __builtin_amdgcn_mfma_f32_16x16x32_bf16(a, b1, acc1, 0, 0, 0);
  acc2 = __builtin_amdgcn_mfma_f32_16x16x32_bf16(a, b2, acc2, 0, 0, 0);

  // epilogue: D[row=4g+r][col=q], h = w*16+q
  const int h = w * 16 + q;
  const float biask = bk[h], biasq = bq[h] * QSCALE, biasv = bv[h];
  #pragma unroll
  for (int r = 0; r < 4; ++r) {
    const long row = row0 + 4 * g + r;
    kb[row * 64 + h] = f2bf(acc0[r] + biask);
    qb[row * 64 + h] = f2bf(acc1[r] + biasq);
    const long bi = row >> 11, tl = row & 2047;
    vt[(bi * 64 + h) * TT + tl] = f2bf(acc2[r] + biasv);
  }
}

// ---------- flash attention, swapped-operand MFMA ---------------------------
// S^T = mfma(K, Q): lane holds S^T[key=4g+r][qcol=lane&15] -> per-lane softmax.
// O^T = mfma(V^T, P^T). 8 waves: w>>2 = strip pair slot, w&3 = key quarter.
__global__ __launch_bounds__(512, 4) void attn_fwd(
    const unsigned short* __restrict__ qb, const unsigned short* __restrict__ kb,
    const unsigned short* __restrict__ vt, float* __restrict__ out) {
  __shared__ alignas(16) unsigned short PsT[8][16][40];  // per wave [q][key]
  __shared__ float accQ[2][3][64][17];
  __shared__ float mlQ[2][3][2][16];

  const int tid = threadIdx.x;
  const int w = tid >> 6, lane = tid & 63;
  const int q = lane & 15, g = lane >> 4;

  const int b = blockIdx.x & 7;
  const int pidx = blockIdx.x >> 3;  // 0..63
  const int pr = w >> 2;             // strip slot (0/1) within block
  const int qs = w & 3;              // key quarter
  const int s = (pr == 0) ? pidx : (127 - pidx);
  const int q0 = s * 16;
  const long base = (long)b * TT;

  const int ntiles = (s + 2) >> 1;   // ceil((s+1)*16 / 32)
  const int t_lo = (qs * ntiles) >> 2;
  const int t_hi = ((qs + 1) * ntiles) >> 2;

  // Q fragments (held whole kernel): B[k=h][col=q], k contiguous per lane
  const short8 Qf0 = *(const short8*)&qb[(base + q0 + q) * 64 + g * 8];
  const short8 Qf1 = *(const short8*)&qb[(base + q0 + q) * 64 + 32 + g * 8];

  const f32x4 z = {0.f, 0.f, 0.f, 0.f};
  float m = -INFINITY, l = 0.f;
  f32x4 o0 = z, o1 = z, o2 = z, o3 = z;
  const int qg = q0 + q;

  for (int t = t_lo; t < t_hi; ++t) {
    const int k0 = t * 32;
    // K A-frags: A[row=key-local=lane&15][k=h contiguous]
    const unsigned short* kp = &kb[(base + k0 + q) * 64];
    const short8 K00 = *(const short8*)&kp[g * 8];
    const short8 K01 = *(const short8*)&kp[32 + g * 8];
    const short8 K10 = *(const short8*)&kp[16 * 64 + g * 8];
    const short8 K11 = *(const short8*)&kp[16 * 64 + 32 + g * 8];

    f32x4 sa = __builtin_amdgcn_mfma_f32_16x16x32_bf16(K00, Qf0, z, 0, 0, 0);
    sa = __builtin_amdgcn_mfma_f32_16x16x32_bf16(K01, Qf1, sa, 0, 0, 0);
    f32x4 sb = __builtin_amdgcn_mfma_f32_16x16x32_bf16(K10, Qf0, z, 0, 0, 0);
    sb = __builtin_amdgcn_mfma_f32_16x16x32_bf16(K11, Qf1, sb, 0, 0, 0);

    // causal mask: key = k0 + kblk*16 + 4g + r  vs  q-row qg
    if (k0 + 31 > q0) {
      #pragma unroll
      for (int r = 0; r < 4; ++r) {
        if (k0 + 4 * g + r > qg) sa[r] = -INFINITY;
        if (k0 + 16 + 4 * g + r > qg) sb[r] = -INFINITY;
      }
    }

    // online softmax (exp2 domain; per-lane rows, reduce only across g)
    float tmax = fmaxf(fmaxf(fmaxf(sa[0], sa[1]), fmaxf(sa[2], sa[3])),
                       fmaxf(fmaxf(sb[0], sb[1]), fmaxf(sb[2], sb[3])));
    tmax = fmaxf(tmax, __shfl_xor(tmax, 16));
    tmax = fmaxf(tmax, __shfl_xor(tmax, 32));
    const float nm = fmaxf(m, tmax);
    const float rs = __builtin_amdgcn_exp2f(m - nm);  // m=-inf -> 0
    float p[8], ps = 0.f;
    #pragma unroll
    for (int r = 0; r < 4; ++r) { p[r] = __builtin_amdgcn_exp2f(sa[r] - nm); ps += p[r]; }
    #pragma unroll
    for (int r = 0; r < 4; ++r) { p[4 + r] = __builtin_amdgcn_exp2f(sb[r] - nm); ps += p[4 + r]; }
    ps += __shfl_xor(ps, 16);
    ps += __shfl_xor(ps, 32);
    l = l * rs + ps;
    m = nm;
    o0 *= rs; o1 *= rs; o2 *= rs; o3 *= rs;

    // V^T A-frags: A[row=h-local=lane&15][k=key contiguous]
    const unsigned short* vp = &vt[((long)b * 64 + q) * TT + k0];
    const short8 V0 = *(const short8*)&vp[g * 8];
    const short8 V1 = *(const short8*)&vp[16 * TT + g * 8];
    const short8 V2 = *(const short8*)&vp[32 * TT + g * 8];
    const short8 V3 = *(const short8*)&vp[48 * TT + g * 8];

    // P^T via per-wave LDS: write [q][key=4g..], read B-frag [q][8g..8g+7]
    us4 plo = {f2bf(p[0]), f2bf(p[1]), f2bf(p[2]), f2bf(p[3])};
    us4 phi = {f2bf(p[4]), f2bf(p[5]), f2bf(p[6]), f2bf(p[7])};
    *(us4*)&PsT[w][q][4 * g] = plo;
    *(us4*)&PsT[w][q][16 + 4 * g] = phi;
    const short8 Pf = *(const short8*)&PsT[w][q][8 * g];

    o0 = __builtin_amdgcn_mfma_f32_16x16x32_bf16(V0, Pf, o0, 0, 0, 0);
    o1 = __builtin_amdgcn_mfma_f32_16x16x32_bf16(V1, Pf, o1, 0, 0, 0);
    o2 = __builtin_amdgcn_mfma_f32_16x16x32_bf16(V2, Pf, o2, 0, 0, 0);
    o3 = __builtin_amdgcn_mfma_f32_16x16x32_bf16(V3, Pf, o3, 0, 0, 0);
  }

  // merge the four key-quarters of each strip
  if (qs != 0) {
    #pragma unroll
    for (int hb = 0; hb < 4; ++hb) {
      const f32x4 a = (hb == 0) ? o0 : (hb == 1) ? o1 : (hb == 2) ? o2 : o3;
      #pragma unroll
      for (int r = 0; r < 4; ++r) accQ[pr][qs - 1][16 * hb + 4 * g + r][q] = a[r];
    }
    mlQ[pr][qs - 1][0][q] = m;  // replicated across g: same value
    mlQ[pr][qs - 1][1][q] = l;
  }
  __syncthreads();
  if (qs == 0) {
    const float m1 = mlQ[pr][0][0][q], l1 = mlQ[pr][0][1][q];
    const float m2 = mlQ[pr][1][0][q], l2 = mlQ[pr][1][1][q];
    const float m3 = mlQ[pr][2][0][q], l3 = mlQ[pr][2][1][q];
    const float M = fmaxf(fmaxf(m, m1), fmaxf(m2, m3));
    const float f0 = __builtin_amdgcn_exp2f(m - M);
    const float f1 = __builtin_amdgcn_exp2f(m1 - M);
    const float f2 = __builtin_amdgcn_exp2f(m2 - M);
    const float f3 = __builtin_amdgcn_exp2f(m3 - M);
    const float invL = 1.f / (l * f0 + l1 * f1 + l2 * f2 + l3 * f3);
    #pragma unroll
    for (int hb = 0; hb < 4; ++hb) {
      const f32x4 a = (hb == 0) ? o0 : (hb == 1) ? o1 : (hb == 2) ? o2 : o3;
      #pragma unroll
      for (int r = 0; r < 4; ++r) {
        const int row = 16 * hb + 4 * g + r;
        const float v = (a[r] * f0 + accQ[pr][0][row][q] * f1 +
                         accQ[pr][1][row][q] * f2 + accQ[pr][2][row][q] * f3) * invL;
        out[(base + q0 + q) * 64 + row] = v;
      }
    }
  }
}

extern "C" void kernel_launch(void* const* d_in, const int* in_sizes, int n_in,
                              void* d_out, int out_size, void* d_ws, size_t ws_size,
                              hipStream_t stream) {
  const float* x  = (const float*)d_in[0];
  const float* Wk = (const float*)d_in[1];
  const float* bk = (const float*)d_in[2];
  const float* Wq = (const float*)d_in[3];
  const float* bq = (const float*)d_in[4];
  const float* Wv = (const float*)d_in[5];
  const float* bv = (const float*)d_in[6];
  float* out = (float*)d_out;

  unsigned short* qbuf = (unsigned short*)d_ws;            // [B*T][64]
  unsigned short* kbuf = qbuf + (size_t)BB * TT * HH;      // [B*T][64]
  unsigned short* vtb  = kbuf + (size_t)BB * TT * HH;      // [B][64][T]
  unsigned short* Wf   = vtb + (size_t)BB * TT * HH;       // [12][32][64][8]

  prep_w<<<dim3(96), 256, 0, stream>>>(Wk, Wq, Wv, Wf);
  qkv_proj<<<dim3(1024), 256, 0, stream>>>(x, bk, bq, bv, Wf, kbuf, qbuf, vtb);
  attn_fwd<<<dim3(512), 512, 0, stream>>>(qbuf, kbuf, vtb, out);
}